// Round 10
// baseline (151.301 us; speedup 1.0000x reference)
//
#include <hip/hip_runtime.h>
#include <hip/hip_bf16.h>

// B=2,S=2048 -> T=4096 tokens; D=1024; N=64 experts; R=64; TOP_K=2.
// Inputs runtime-detected f32 vs bf16 (measured: f32). Outputs f32 flat:
// [0,262144) proj; [262144,270336) idx; [270336,278528) w.
// R10: score LDS double-buffered (1 barrier/chunk, prefetch overlaps compute);
// egemm staging all-b128 (10 vs 40 vmem inst/thread/chunk), token addrs
// hoisted. Compute tiles + reduce orders unchanged from R9 (absmax-stable).
// Fixed harness overhead in dur_us: ~44us d_ws poison fill + ~6us restores.
// d_ws: f32 w[t*2] (32KB); int cnt[64]; int list[64*1024] (256KB).

typedef unsigned short u16;
typedef unsigned int u32;
typedef __attribute__((ext_vector_type(8))) short short8;
typedef __attribute__((ext_vector_type(4))) float f32x4;

__device__ __forceinline__ float bf2f(u16 u) {
    u32 v = ((u32)u) << 16; float f; __builtin_memcpy(&f, &v, 4); return f;
}
__device__ __forceinline__ u16 f2bf(float f) {  // RNE
    u32 u; __builtin_memcpy(&u, &f, 4);
    u32 r = u + 0x7fff + ((u >> 16) & 1);
    return (u16)(r >> 16);
}
__device__ __forceinline__ u32 pack2(float a, float b) {
    return ((u32)f2bf(b) << 16) | (u32)f2bf(a);
}

#define T_TOKENS 4096
#define DDIM 1024
#define NEXP 64
#define RDIM 64
#define LCAP 1024
#define OUT_IDX_OFF 262144
#define OUT_W_OFF 270336

struct LdBF {
    const u16* p;
    __device__ __forceinline__ float4 ld4(size_t i) const {
        ushort4 v = *(const ushort4*)(p + i);
        return make_float4(bf2f(v.x), bf2f(v.y), bf2f(v.z), bf2f(v.w));
    }
    __device__ __forceinline__ float ld1(size_t i) const { return bf2f(p[i]); }
};
struct LdF32 {
    const float* p;
    __device__ __forceinline__ float4 ld4(size_t i) const { return *(const float4*)(p + i); }
    __device__ __forceinline__ float ld1(size_t i) const { return p[i]; }
};

// in-block dtype probe: 1 if f32, 0 if bf16 (all blocks same verdict).
__device__ __forceinline__ int detect_f32(const u16* x, int* lds_cnt) {
    if (threadIdx.x == 0) *lds_cnt = 0;
    __syncthreads();
    if (threadIdx.x < 256) {
        unsigned e = (x[threadIdx.x] >> 7) & 0xFF;
        if (e >= 0x68 && e <= 0x88) atomicAdd(lds_cnt, 1);
    }
    __syncthreads();
    int f = (*lds_cnt < 200) ? 1 : 0;
    __syncthreads();
    return f;
}

// ---------------- Kernel A: score GEMM + top2 + softmax + expert lists ----
// 256 blocks x 256 thr; 16 tokens/block; K-chunks of 64, double-buffered.
// Lane roles and accumulation order identical to R9 (absmax-stable).
template <class LD>
__device__ __forceinline__ void score_body(LD xld, LD rwld,
                                           float* xs /*2*16*68*/, float* wt /*2*64*68*/,
                                           float* sc /*16*65*/,
                                           float* out, float* wsW,
                                           int* wsCnt, int* wsList) {
    const int tid = threadIdx.x;
    const size_t t0 = (size_t)blockIdx.x * 16;
    const int wv = tid >> 6;
    const int lane = tid & 63;
    const int tg = lane & 1;
    const int eg = (lane >> 1) & 7;
    const int kql = (lane >> 4) & 3;
    const int dd = 4 * kql + 16 * wv;

    // zero this block's 16x64 proj out-region (egemm atomically accumulates)
    {
        float4 z = make_float4(0.f, 0.f, 0.f, 0.f);
        ((float4*)out)[(size_t)blockIdx.x * 256 + tid] = z;
    }

    const int sm = tid >> 4;            // staging roles (coalesced)
    const int sd4 = (tid & 15) * 4;

    float acc[8][8];
#pragma unroll
    for (int mi = 0; mi < 8; ++mi)
#pragma unroll
        for (int ei = 0; ei < 8; ++ei) acc[mi][ei] = 0.f;

    // stage chunk 0 into buffer 0
    {
        float4 px = xld.ld4((t0 + sm) * DDIM + sd4);
        *(float4*)&xs[sm * 68 + sd4] = px;
#pragma unroll
        for (int h = 0; h < 4; ++h) {
            int i4 = tid + h * 256;
            float4 pw = rwld.ld4((size_t)(i4 >> 4) * DDIM + (i4 & 15) * 4);
            *(float4*)&wt[(i4 >> 4) * 68 + (i4 & 15) * 4] = pw;
        }
    }
    __syncthreads();

    for (int kc = 0; kc < 16; ++kc) {
        float4 px; float4 pw[4];
        if (kc < 15) {                       // issue next-chunk loads early
            px = xld.ld4((t0 + sm) * DDIM + (kc + 1) * 64 + sd4);
#pragma unroll
            for (int h = 0; h < 4; ++h) {
                int i4 = tid + h * 256;
                pw[h] = rwld.ld4((size_t)(i4 >> 4) * DDIM + (kc + 1) * 64 + (i4 & 15) * 4);
            }
        }

        const float* xsb = xs + (kc & 1) * (16 * 68);
        const float* wtb = wt + (kc & 1) * (64 * 68);
        float4 xv[8], wv4[8];
#pragma unroll
        for (int mi = 0; mi < 8; ++mi)
            xv[mi] = *(const float4*)&xsb[(tg + 2 * mi) * 68 + dd];
#pragma unroll
        for (int ei = 0; ei < 8; ++ei)
            wv4[ei] = *(const float4*)&wtb[(eg + 8 * ei) * 68 + dd];
#pragma unroll
        for (int mi = 0; mi < 8; ++mi)
#pragma unroll
            for (int ei = 0; ei < 8; ++ei)
                acc[mi][ei] += xv[mi].x * wv4[ei].x + xv[mi].y * wv4[ei].y +
                               xv[mi].z * wv4[ei].z + xv[mi].w * wv4[ei].w;

        if (kc < 15) {                       // write next chunk to other buffer
            float* xsn = xs + ((kc + 1) & 1) * (16 * 68);
            float* wtn = wt + ((kc + 1) & 1) * (64 * 68);
            *(float4*)&xsn[sm * 68 + sd4] = px;
#pragma unroll
            for (int h = 0; h < 4; ++h) {
                int i4 = tid + h * 256;
                *(float4*)&wtn[(i4 >> 4) * 68 + (i4 & 15) * 4] = pw[h];
            }
            __syncthreads();
        }
    }

    // in-wave k-quad reduce (deterministic tree over kql)
#pragma unroll
    for (int mi = 0; mi < 8; ++mi)
#pragma unroll
        for (int ei = 0; ei < 8; ++ei) {
            float v = acc[mi][ei];
            v += __shfl_xor(v, 16, 64);
            v += __shfl_xor(v, 32, 64);
            acc[mi][ei] = v;
        }
    __syncthreads();

    // cross-wave reduce: sequential wave phases (deterministic order)
    for (int w = 0; w < 4; ++w) {
        if (wv == w && kql == 0) {
#pragma unroll
            for (int mi = 0; mi < 8; ++mi)
#pragma unroll
                for (int ei = 0; ei < 8; ++ei) {
                    int idx = (tg + 2 * mi) * 65 + eg + 8 * ei;
                    sc[idx] = (w == 0) ? acc[mi][ei] : sc[idx] + acc[mi][ei];
                }
        }
        __syncthreads();
    }

    if (tid < 16) {
        const float* s = &sc[tid * 65];
        float best = -1e30f, secv = -1e30f;
        int bi = 0, si = 0;
        for (int j = 0; j < NEXP; ++j) {
            float v = s[j];
            if (v > best) { secv = best; si = bi; best = v; bi = j; }
            else if (v > secv) { secv = v; si = j; }
        }
        float w0 = 1.0f / (1.0f + expf(secv - best));
        float w1 = 1.0f - w0;
        size_t t = t0 + tid;
        out[OUT_IDX_OFF + t * 2 + 0] = (float)bi;
        out[OUT_IDX_OFF + t * 2 + 1] = (float)si;
        out[OUT_W_OFF + t * 2 + 0] = w0;
        out[OUT_W_OFF + t * 2 + 1] = w1;
        wsW[t * 2 + 0] = w0;
        wsW[t * 2 + 1] = w1;
        int p0 = atomicAdd(&wsCnt[bi], 1);
        if (p0 < LCAP) wsList[bi * LCAP + p0] = (int)(t * 2 + 0);
        int p1 = atomicAdd(&wsCnt[si], 1);
        if (p1 < LCAP) wsList[si * LCAP + p1] = (int)(t * 2 + 1);
    }
}

__global__ __launch_bounds__(256, 1) void score_topk(const void* x, const void* rw,
                                                     float* out, float* wsW,
                                                     int* wsCnt, int* wsList) {
    __shared__ float xs[2 * 16 * 68];
    __shared__ float wt[2 * 64 * 68];
    __shared__ float sc[16 * 65];
    __shared__ int dc;
    int f = detect_f32((const u16*)x, &dc);
    if (f)
        score_body(LdF32{(const float*)x}, LdF32{(const float*)rw}, xs, wt, sc, out, wsW, wsCnt, wsList);
    else
        score_body(LdBF{(const u16*)x}, LdBF{(const u16*)rw}, xs, wt, sc, out, wsW, wsCnt, wsList);
}

// ---------------- Kernel B: per-expert bf16 MFMA GEMM, 1 tile/block --------
// 1024 blocks: e = bid&63 (XCD = e%8), ti = bid>>6 (rows [16ti,16ti+16)).
// All staging loads b128; token base addresses hoisted out of k-loop.
template <class LD>
__device__ __forceinline__ void egemm_body(LD xld, LD nld,
                                           const int* wsCnt, const int* wsList,
                                           const float* wsW, float* out,
                                           u16* Ab /*16*136*/, u16* Bb /*64*136*/,
                                           int* entL /*16*/) {
    const int tid = threadIdx.x;
    const int e = blockIdx.x & 63;
    const int ti = blockIdx.x >> 6;
    const int cntE = min(wsCnt[e], LCAP);
    const int base = ti * 16;
    if (base >= cntE) return;                    // uniform exit for idle tiles
    const int valid = min(16, cntE - base);
    const int wv = tid >> 6;
    const int lane = tid & 63;
    const int l15 = lane & 15, quad = lane >> 4;
    const size_t nbase = (size_t)e * (DDIM * RDIM);

    if (tid < 16)
        entL[tid] = wsList[e * LCAP + base + min(tid, valid - 1)];
    __syncthreads();

    // A staging role (fixed across chunks): row = tid&15, k-quads kq0, kq0+16
    const int rowA = tid & 15;
    const int kq0 = tid >> 4;                    // 0..15
    const size_t ttA = (size_t)(entL[rowA] >> 1) * DDIM;

    f32x4 acc = {0.f, 0.f, 0.f, 0.f};

    for (int kc = 0; kc < 8; ++kc) {
        const int k0c = kc * 128;
        if (kc > 0) __syncthreads();
        // B: 128k x 64r -> bf16 pairs along k. 8 b128 loads/thread.
#pragma unroll
        for (int h = 0; h < 4; ++h) {
            int u = tid + h * 256;               // 0..1023
            int rq = u & 15, kp = u >> 4;        // r-quad, k-pair
            float4 g0 = nld.ld4(nbase + (size_t)(k0c + 2 * kp) * RDIM + 4 * rq);
            float4 g1 = nld.ld4(nbase + (size_t)(k0c + 2 * kp + 1) * RDIM + 4 * rq);
            u32* bw = (u32*)Bb;
            bw[(4 * rq + 0) * 68 + kp] = pack2(g0.x, g1.x);
            bw[(4 * rq + 1) * 68 + kp] = pack2(g0.y, g1.y);
            bw[(4 * rq + 2) * 68 + kp] = pack2(g0.z, g1.z);
            bw[(4 * rq + 3) * 68 + kp] = pack2(g0.w, g1.w);
        }
        // A: 16 rows x 128k. 2 b128 loads/thread (k-contiguous).
        {
            float4 ga0 = xld.ld4(ttA + k0c + 4 * kq0);
            float4 ga1 = xld.ld4(ttA + k0c + 4 * (kq0 + 16));
            u32* aw = (u32*)Ab;
            aw[rowA * 68 + 2 * kq0 + 0]  = pack2(ga0.x, ga0.y);
            aw[rowA * 68 + 2 * kq0 + 1]  = pack2(ga0.z, ga0.w);
            aw[rowA * 68 + 2 * kq0 + 32] = pack2(ga1.x, ga1.y);
            aw[rowA * 68 + 2 * kq0 + 33] = pack2(ga1.z, ga1.w);
        }
        __syncthreads();

#pragma unroll
        for (int ko = 0; ko < 4; ++ko) {
            int kofs = ko * 32 + quad * 8;
            short8 bfr = *(const short8*)&Bb[(16 * wv + l15) * 136 + kofs];
            short8 af = *(const short8*)&Ab[l15 * 136 + kofs];
            acc = __builtin_amdgcn_mfma_f32_16x16x32_bf16(af, bfr, acc, 0, 0, 0);
        }
    }

    // D: row (token m) = quad*4+reg, col r = 16*wv + l15
#pragma unroll
    for (int reg = 0; reg < 4; ++reg) {
        int m = quad * 4 + reg;
        if (m < valid) {
            int t2 = entL[m];
            atomicAdd(&out[(size_t)(t2 >> 1) * RDIM + 16 * wv + l15], wsW[t2] * acc[reg]);
        }
    }
}

__global__ __launch_bounds__(256) void expert_gemm(const void* x, const void* neurons,
                                                   const int* wsCnt, const int* wsList,
                                                   const float* wsW, float* out) {
    __shared__ u16 Ab[16 * 136];
    __shared__ u16 Bb[64 * 136];
    __shared__ int entL[16];
    __shared__ int dc;
    int f = detect_f32((const u16*)x, &dc);
    if (f)
        egemm_body(LdF32{(const float*)x}, LdF32{(const float*)neurons}, wsCnt, wsList, wsW, out, Ab, Bb, entL);
    else
        egemm_body(LdBF{(const u16*)x}, LdBF{(const u16*)neurons}, wsCnt, wsList, wsW, out, Ab, Bb, entL);
}

extern "C" void kernel_launch(void* const* d_in, const int* in_sizes, int n_in,
                              void* d_out, int out_size, void* d_ws, size_t ws_size,
                              hipStream_t stream) {
    const void* x = d_in[0];
    const void* rw = d_in[1];
    const void* neurons = d_in[2];
    float* out = (float*)d_out;

    char* wsc = (char*)d_ws;
    float* wsW = (float*)wsc;                                  // 32 KB
    int* wsCnt = (int*)(wsc + 32 * 1024);                      // 256 B
    int* wsList = (int*)((char*)wsCnt + 256);                  // 256 KB

    hipMemsetAsync(wsCnt, 0, 256, stream);
    score_topk<<<256, 256, 0, stream>>>(x, rw, out, wsW, wsCnt, wsList);
    expert_gemm<<<1024, 256, 0, stream>>>(x, neurons, wsCnt, wsList, wsW, out);
}

// Round 11
// 138.410 us; speedup vs baseline: 1.0931x; 1.0931x over previous
//
#include <hip/hip_runtime.h>
#include <hip/hip_bf16.h>

// B=2,S=2048 -> T=4096 tokens; D=1024; N=64 experts; R=64; TOP_K=2.
// Inputs runtime-detected f32 vs bf16 (measured: f32). Outputs f32 flat:
// [0,262144) proj; [262144,270336) idx; [270336,278528) w.
// R11: R10's score dbuf reverted (regressed 42->70us: cross-wave ds_read/write
// bank conflicts 1.16M, VGPR 80). Root cause of score's 42us was 1 block/CU,
// zero TLP -> k-split 4: grid 1024 partial-score blocks (4/CU, R9 compute
// body verbatim, 4 chunks), partials to ws; combine_topk sums 4 partials in
// fixed order + unchanged top-2/softmax/list code. egemm = R10 (b128 staging).
// Fixed harness overhead in dur_us: ~44us d_ws poison fill + restores.
// d_ws: f32 w[t*2] (32KB); int cnt[64]; int list[64*1024] (256KB);
//       f32 psc[4096][4][64] (4MB).

typedef unsigned short u16;
typedef unsigned int u32;
typedef __attribute__((ext_vector_type(8))) short short8;
typedef __attribute__((ext_vector_type(4))) float f32x4;

__device__ __forceinline__ float bf2f(u16 u) {
    u32 v = ((u32)u) << 16; float f; __builtin_memcpy(&f, &v, 4); return f;
}
__device__ __forceinline__ u16 f2bf(float f) {  // RNE
    u32 u; __builtin_memcpy(&u, &f, 4);
    u32 r = u + 0x7fff + ((u >> 16) & 1);
    return (u16)(r >> 16);
}
__device__ __forceinline__ u32 pack2(float a, float b) {
    return ((u32)f2bf(b) << 16) | (u32)f2bf(a);
}

#define T_TOKENS 4096
#define DDIM 1024
#define NEXP 64
#define RDIM 64
#define LCAP 1024
#define OUT_IDX_OFF 262144
#define OUT_W_OFF 270336

struct LdBF {
    const u16* p;
    __device__ __forceinline__ float4 ld4(size_t i) const {
        ushort4 v = *(const ushort4*)(p + i);
        return make_float4(bf2f(v.x), bf2f(v.y), bf2f(v.z), bf2f(v.w));
    }
    __device__ __forceinline__ float ld1(size_t i) const { return bf2f(p[i]); }
};
struct LdF32 {
    const float* p;
    __device__ __forceinline__ float4 ld4(size_t i) const { return *(const float4*)(p + i); }
    __device__ __forceinline__ float ld1(size_t i) const { return p[i]; }
};

// in-block dtype probe: 1 if f32, 0 if bf16 (all blocks same verdict).
__device__ __forceinline__ int detect_f32(const u16* x, int* lds_cnt) {
    if (threadIdx.x == 0) *lds_cnt = 0;
    __syncthreads();
    if (threadIdx.x < 256) {
        unsigned e = (x[threadIdx.x] >> 7) & 0xFF;
        if (e >= 0x68 && e <= 0x88) atomicAdd(lds_cnt, 1);
    }
    __syncthreads();
    int f = (*lds_cnt < 200) ? 1 : 0;
    __syncthreads();
    return f;
}

// ------------- Kernel A: partial score GEMM (k-split 4) --------------------
// 1024 blocks x 256 thr: g = bid>>2 (16 tokens), p = bid&3 (k in [256p,256p+256)).
// Compute body identical to R9 (4 chunks of 64 instead of 16).
template <class LD>
__device__ __forceinline__ void spart_body(LD xld, LD rwld,
                                           float* xs /*16*68*/, float* wt /*64*68*/,
                                           float* sc /*16*65*/, float* psc) {
    const int tid = threadIdx.x;
    const int g = blockIdx.x >> 2;
    const int p = blockIdx.x & 3;
    const size_t t0 = (size_t)g * 16;
    const int kbase = p * 256;
    const int wv = tid >> 6;
    const int lane = tid & 63;
    const int tg = lane & 1;
    const int eg = (lane >> 1) & 7;
    const int kql = (lane >> 4) & 3;
    const int dd = 4 * kql + 16 * wv;

    const int sm = tid >> 4;            // staging roles (coalesced)
    const int sd4 = (tid & 15) * 4;

    float acc[8][8];
#pragma unroll
    for (int mi = 0; mi < 8; ++mi)
#pragma unroll
        for (int ei = 0; ei < 8; ++ei) acc[mi][ei] = 0.f;

    float4 px = xld.ld4((t0 + sm) * DDIM + kbase + sd4);
    float4 pw[4];
#pragma unroll
    for (int h = 0; h < 4; ++h) {
        int i4 = tid + h * 256;
        pw[h] = rwld.ld4((size_t)(i4 >> 4) * DDIM + kbase + (i4 & 15) * 4);
    }

    for (int kc = 0; kc < 4; ++kc) {
        if (kc > 0) __syncthreads();
        *(float4*)&xs[sm * 68 + sd4] = px;
#pragma unroll
        for (int h = 0; h < 4; ++h) {
            int i4 = tid + h * 256;
            *(float4*)&wt[(i4 >> 4) * 68 + (i4 & 15) * 4] = pw[h];
        }
        __syncthreads();

        if (kc < 3) {
            px = xld.ld4((t0 + sm) * DDIM + kbase + (kc + 1) * 64 + sd4);
#pragma unroll
            for (int h = 0; h < 4; ++h) {
                int i4 = tid + h * 256;
                pw[h] = rwld.ld4((size_t)(i4 >> 4) * DDIM + kbase + (kc + 1) * 64 + (i4 & 15) * 4);
            }
        }

        float4 xv[8], wv4[8];
#pragma unroll
        for (int mi = 0; mi < 8; ++mi)
            xv[mi] = *(const float4*)&xs[(tg + 2 * mi) * 68 + dd];
#pragma unroll
        for (int ei = 0; ei < 8; ++ei)
            wv4[ei] = *(const float4*)&wt[(eg + 8 * ei) * 68 + dd];
#pragma unroll
        for (int mi = 0; mi < 8; ++mi)
#pragma unroll
            for (int ei = 0; ei < 8; ++ei)
                acc[mi][ei] += xv[mi].x * wv4[ei].x + xv[mi].y * wv4[ei].y +
                               xv[mi].z * wv4[ei].z + xv[mi].w * wv4[ei].w;
    }

    // in-wave k-quad reduce (deterministic)
#pragma unroll
    for (int mi = 0; mi < 8; ++mi)
#pragma unroll
        for (int ei = 0; ei < 8; ++ei) {
            float v = acc[mi][ei];
            v += __shfl_xor(v, 16, 64);
            v += __shfl_xor(v, 32, 64);
            acc[mi][ei] = v;
        }
    __syncthreads();

    // cross-wave reduce: sequential wave phases (deterministic)
    for (int w = 0; w < 4; ++w) {
        if (wv == w && kql == 0) {
#pragma unroll
            for (int mi = 0; mi < 8; ++mi)
#pragma unroll
                for (int ei = 0; ei < 8; ++ei) {
                    int idx = (tg + 2 * mi) * 65 + eg + 8 * ei;
                    sc[idx] = (w == 0) ? acc[mi][ei] : sc[idx] + acc[mi][ei];
                }
        }
        __syncthreads();
    }

    // write partial 16x64 tile: psc[(t0+m)*4 + p][e], coalesced float4
    {
        int m = tid >> 4, e4 = (tid & 15) * 4;
        float4 v = *(const float4*)&sc[m * 65 + e4];
        *(float4*)&psc[((t0 + m) * 4 + p) * 64 + e4] = v;
    }
}

__global__ __launch_bounds__(256) void score_partial(const void* x, const void* rw,
                                                     float* psc) {
    __shared__ float xs[16 * 68];
    __shared__ float wt[64 * 68];
    __shared__ float sc[16 * 65];
    __shared__ int dc;
    int f = detect_f32((const u16*)x, &dc);
    if (f)
        spart_body(LdF32{(const float*)x}, LdF32{(const float*)rw}, xs, wt, sc, psc);
    else
        spart_body(LdBF{(const u16*)x}, LdBF{(const u16*)rw}, xs, wt, sc, psc);
}

// ------------- Kernel A2: combine partials + top2 + softmax + lists --------
// 256 blocks x 256 thr; 16 tokens/block. Fixed p0+p1+p2+p3 order.
__global__ __launch_bounds__(256) void combine_topk(const float* __restrict__ psc,
                                                    float* out, float* wsW,
                                                    int* wsCnt, int* wsList) {
    __shared__ float sc[16 * 65];
    const int tid = threadIdx.x;
    const size_t t0 = (size_t)blockIdx.x * 16;

    // zero this block's 16x64 proj out-region (egemm atomically accumulates)
    {
        float4 z = make_float4(0.f, 0.f, 0.f, 0.f);
        ((float4*)out)[(size_t)blockIdx.x * 256 + tid] = z;
    }

    {
        int m = tid >> 4, e4 = (tid & 15) * 4;
        const float* pp = &psc[(t0 + m) * 4 * 64 + e4];
        float4 s = *(const float4*)(pp + 0 * 64);
        float4 s1 = *(const float4*)(pp + 1 * 64);
        float4 s2 = *(const float4*)(pp + 2 * 64);
        float4 s3 = *(const float4*)(pp + 3 * 64);
        s.x = ((s.x + s1.x) + s2.x) + s3.x;
        s.y = ((s.y + s1.y) + s2.y) + s3.y;
        s.z = ((s.z + s1.z) + s2.z) + s3.z;
        s.w = ((s.w + s1.w) + s2.w) + s3.w;
        *(float4*)&sc[m * 65 + e4] = s;
    }
    __syncthreads();

    if (tid < 16) {
        const float* s = &sc[tid * 65];
        float best = -1e30f, secv = -1e30f;
        int bi = 0, si = 0;
        for (int j = 0; j < NEXP; ++j) {
            float v = s[j];
            if (v > best) { secv = best; si = bi; best = v; bi = j; }
            else if (v > secv) { secv = v; si = j; }
        }
        float w0 = 1.0f / (1.0f + expf(secv - best));
        float w1 = 1.0f - w0;
        size_t t = t0 + tid;
        out[OUT_IDX_OFF + t * 2 + 0] = (float)bi;
        out[OUT_IDX_OFF + t * 2 + 1] = (float)si;
        out[OUT_W_OFF + t * 2 + 0] = w0;
        out[OUT_W_OFF + t * 2 + 1] = w1;
        wsW[t * 2 + 0] = w0;
        wsW[t * 2 + 1] = w1;
        int p0 = atomicAdd(&wsCnt[bi], 1);
        if (p0 < LCAP) wsList[bi * LCAP + p0] = (int)(t * 2 + 0);
        int p1 = atomicAdd(&wsCnt[si], 1);
        if (p1 < LCAP) wsList[si * LCAP + p1] = (int)(t * 2 + 1);
    }
}

// ---------------- Kernel B: per-expert bf16 MFMA GEMM (R10, unchanged) -----
template <class LD>
__device__ __forceinline__ void egemm_body(LD xld, LD nld,
                                           const int* wsCnt, const int* wsList,
                                           const float* wsW, float* out,
                                           u16* Ab /*16*136*/, u16* Bb /*64*136*/,
                                           int* entL /*16*/) {
    const int tid = threadIdx.x;
    const int e = blockIdx.x & 63;
    const int ti = blockIdx.x >> 6;
    const int cntE = min(wsCnt[e], LCAP);
    const int base = ti * 16;
    if (base >= cntE) return;
    const int valid = min(16, cntE - base);
    const int wv = tid >> 6;
    const int lane = tid & 63;
    const int l15 = lane & 15, quad = lane >> 4;
    const size_t nbase = (size_t)e * (DDIM * RDIM);

    if (tid < 16)
        entL[tid] = wsList[e * LCAP + base + min(tid, valid - 1)];
    __syncthreads();

    const int rowA = tid & 15;
    const int kq0 = tid >> 4;
    const size_t ttA = (size_t)(entL[rowA] >> 1) * DDIM;

    f32x4 acc = {0.f, 0.f, 0.f, 0.f};

    for (int kc = 0; kc < 8; ++kc) {
        const int k0c = kc * 128;
        if (kc > 0) __syncthreads();
#pragma unroll
        for (int h = 0; h < 4; ++h) {
            int u = tid + h * 256;
            int rq = u & 15, kp = u >> 4;
            float4 g0 = nld.ld4(nbase + (size_t)(k0c + 2 * kp) * RDIM + 4 * rq);
            float4 g1 = nld.ld4(nbase + (size_t)(k0c + 2 * kp + 1) * RDIM + 4 * rq);
            u32* bw = (u32*)Bb;
            bw[(4 * rq + 0) * 68 + kp] = pack2(g0.x, g1.x);
            bw[(4 * rq + 1) * 68 + kp] = pack2(g0.y, g1.y);
            bw[(4 * rq + 2) * 68 + kp] = pack2(g0.z, g1.z);
            bw[(4 * rq + 3) * 68 + kp] = pack2(g0.w, g1.w);
        }
        {
            float4 ga0 = xld.ld4(ttA + k0c + 4 * kq0);
            float4 ga1 = xld.ld4(ttA + k0c + 4 * (kq0 + 16));
            u32* aw = (u32*)Ab;
            aw[rowA * 68 + 2 * kq0 + 0]  = pack2(ga0.x, ga0.y);
            aw[rowA * 68 + 2 * kq0 + 1]  = pack2(ga0.z, ga0.w);
            aw[rowA * 68 + 2 * kq0 + 32] = pack2(ga1.x, ga1.y);
            aw[rowA * 68 + 2 * kq0 + 33] = pack2(ga1.z, ga1.w);
        }
        __syncthreads();

#pragma unroll
        for (int ko = 0; ko < 4; ++ko) {
            int kofs = ko * 32 + quad * 8;
            short8 bfr = *(const short8*)&Bb[(16 * wv + l15) * 136 + kofs];
            short8 af = *(const short8*)&Ab[l15 * 136 + kofs];
            acc = __builtin_amdgcn_mfma_f32_16x16x32_bf16(af, bfr, acc, 0, 0, 0);
        }
    }

#pragma unroll
    for (int reg = 0; reg < 4; ++reg) {
        int m = quad * 4 + reg;
        if (m < valid) {
            int t2 = entL[m];
            atomicAdd(&out[(size_t)(t2 >> 1) * RDIM + 16 * wv + l15], wsW[t2] * acc[reg]);
        }
    }
}

__global__ __launch_bounds__(256) void expert_gemm(const void* x, const void* neurons,
                                                   const int* wsCnt, const int* wsList,
                                                   const float* wsW, float* out) {
    __shared__ u16 Ab[16 * 136];
    __shared__ u16 Bb[64 * 136];
    __shared__ int entL[16];
    __shared__ int dc;
    int f = detect_f32((const u16*)x, &dc);
    if (f)
        egemm_body(LdF32{(const float*)x}, LdF32{(const float*)neurons}, wsCnt, wsList, wsW, out, Ab, Bb, entL);
    else
        egemm_body(LdBF{(const u16*)x}, LdBF{(const u16*)neurons}, wsCnt, wsList, wsW, out, Ab, Bb, entL);
}

extern "C" void kernel_launch(void* const* d_in, const int* in_sizes, int n_in,
                              void* d_out, int out_size, void* d_ws, size_t ws_size,
                              hipStream_t stream) {
    const void* x = d_in[0];
    const void* rw = d_in[1];
    const void* neurons = d_in[2];
    float* out = (float*)d_out;

    char* wsc = (char*)d_ws;
    float* wsW = (float*)wsc;                                  // 32 KB
    int* wsCnt = (int*)(wsc + 32 * 1024);                      // 256 B
    int* wsList = (int*)((char*)wsCnt + 256);                  // 256 KB
    float* psc = (float*)((char*)wsList + (size_t)NEXP * LCAP * 4);  // 4 MB

    hipMemsetAsync(wsCnt, 0, 256, stream);
    score_partial<<<1024, 256, 0, stream>>>(x, rw, psc);
    combine_topk<<<256, 256, 0, stream>>>(psc, out, wsW, wsCnt, wsList);
    expert_gemm<<<1024, 256, 0, stream>>>(x, neurons, wsCnt, wsList, wsW, out);
}

// Round 13
// 130.688 us; speedup vs baseline: 1.1577x; 1.0591x over previous
//
#include <hip/hip_runtime.h>
#include <hip/hip_bf16.h>

// B=2,S=2048 -> T=4096 tokens; D=1024; N=64 experts; R=64; TOP_K=2.
// Inputs runtime-detected f32 vs bf16 (measured: f32). Outputs f32 flat:
// [0,262144) proj; [262144,270336) idx; [270336,278528) w.
// R13: re-land best measured parts. R12 coop kernel FAILED under graph capture
// (grid.sync not preserved on replay -> races, post-timing absmax 3.79; no
// grid-wide sync in this harness). Composition: R9 score_topk verbatim
// (128.3us best wall; single dispatch, M8E8 tile) + R11 egemm verbatim
// (b128 staging, 1024 blocks). 3 dispatches, no cooperative anything.
// d_ws: f32 w[t*2] (32KB); int cnt[64]; int list[64*1024] (256KB).

typedef unsigned short u16;
typedef unsigned int u32;
typedef __attribute__((ext_vector_type(8))) short short8;
typedef __attribute__((ext_vector_type(4))) float f32x4;

__device__ __forceinline__ float bf2f(u16 u) {
    u32 v = ((u32)u) << 16; float f; __builtin_memcpy(&f, &v, 4); return f;
}
__device__ __forceinline__ u16 f2bf(float f) {  // RNE
    u32 u; __builtin_memcpy(&u, &f, 4);
    u32 r = u + 0x7fff + ((u >> 16) & 1);
    return (u16)(r >> 16);
}
__device__ __forceinline__ u32 pack2(float a, float b) {
    return ((u32)f2bf(b) << 16) | (u32)f2bf(a);
}

#define T_TOKENS 4096
#define DDIM 1024
#define NEXP 64
#define RDIM 64
#define LCAP 1024
#define OUT_IDX_OFF 262144
#define OUT_W_OFF 270336

struct LdBF {
    const u16* p;
    __device__ __forceinline__ float4 ld4(size_t i) const {
        ushort4 v = *(const ushort4*)(p + i);
        return make_float4(bf2f(v.x), bf2f(v.y), bf2f(v.z), bf2f(v.w));
    }
    __device__ __forceinline__ float ld1(size_t i) const { return bf2f(p[i]); }
};
struct LdF32 {
    const float* p;
    __device__ __forceinline__ float4 ld4(size_t i) const { return *(const float4*)(p + i); }
    __device__ __forceinline__ float ld1(size_t i) const { return p[i]; }
};

// in-block dtype probe: 1 if f32, 0 if bf16 (all blocks same verdict).
__device__ __forceinline__ int detect_f32(const u16* x, int* lds_cnt) {
    if (threadIdx.x == 0) *lds_cnt = 0;
    __syncthreads();
    if (threadIdx.x < 256) {
        unsigned e = (x[threadIdx.x] >> 7) & 0xFF;
        if (e >= 0x68 && e <= 0x88) atomicAdd(lds_cnt, 1);
    }
    __syncthreads();
    int f = (*lds_cnt < 200) ? 1 : 0;
    __syncthreads();
    return f;
}

// ---------------- Kernel A: score GEMM + top2 + softmax + expert lists ----
// 256 blocks x 256 thr; 16 tokens/block; K-chunks of 64. (R9 verbatim.)
// Lane: tg=lane&1 (tokens tg+2mi), eg=(lane>>1)&7 (experts eg+8ei),
// kql=(lane>>4)&3; k-quad dd = 4*kql + 16*wv. Per thread 8x8 acc.
template <class LD>
__device__ __forceinline__ void score_body(LD xld, LD rwld,
                                           float* xs /*16*68*/, float* wt /*64*68*/,
                                           float* sc /*16*65*/,
                                           float* out, float* wsW,
                                           int* wsCnt, int* wsList) {
    const int tid = threadIdx.x;
    const size_t t0 = (size_t)blockIdx.x * 16;
    const int wv = tid >> 6;
    const int lane = tid & 63;
    const int tg = lane & 1;
    const int eg = (lane >> 1) & 7;
    const int kql = (lane >> 4) & 3;
    const int dd = 4 * kql + 16 * wv;

    // zero this block's 16x64 proj out-region (egemm atomically accumulates)
    {
        float4 z = make_float4(0.f, 0.f, 0.f, 0.f);
        ((float4*)out)[(size_t)blockIdx.x * 256 + tid] = z;
    }

    const int sm = tid >> 4;            // staging roles (coalesced)
    const int sd4 = (tid & 15) * 4;

    float acc[8][8];
#pragma unroll
    for (int mi = 0; mi < 8; ++mi)
#pragma unroll
        for (int ei = 0; ei < 8; ++ei) acc[mi][ei] = 0.f;

    float4 px = xld.ld4((t0 + sm) * DDIM + sd4);
    float4 pw[4];
#pragma unroll
    for (int h = 0; h < 4; ++h) {
        int i4 = tid + h * 256;
        pw[h] = rwld.ld4((size_t)(i4 >> 4) * DDIM + (i4 & 15) * 4);
    }

    for (int kc = 0; kc < 16; ++kc) {
        if (kc > 0) __syncthreads();
        *(float4*)&xs[sm * 68 + sd4] = px;
#pragma unroll
        for (int h = 0; h < 4; ++h) {
            int i4 = tid + h * 256;
            *(float4*)&wt[(i4 >> 4) * 68 + (i4 & 15) * 4] = pw[h];
        }
        __syncthreads();

        if (kc < 15) {
            px = xld.ld4((t0 + sm) * DDIM + (kc + 1) * 64 + sd4);
#pragma unroll
            for (int h = 0; h < 4; ++h) {
                int i4 = tid + h * 256;
                pw[h] = rwld.ld4((size_t)(i4 >> 4) * DDIM + (kc + 1) * 64 + (i4 & 15) * 4);
            }
        }

        float4 xv[8], wv4[8];
#pragma unroll
        for (int mi = 0; mi < 8; ++mi)
            xv[mi] = *(const float4*)&xs[(tg + 2 * mi) * 68 + dd];
#pragma unroll
        for (int ei = 0; ei < 8; ++ei)
            wv4[ei] = *(const float4*)&wt[(eg + 8 * ei) * 68 + dd];
#pragma unroll
        for (int mi = 0; mi < 8; ++mi)
#pragma unroll
            for (int ei = 0; ei < 8; ++ei)
                acc[mi][ei] += xv[mi].x * wv4[ei].x + xv[mi].y * wv4[ei].y +
                               xv[mi].z * wv4[ei].z + xv[mi].w * wv4[ei].w;
    }

    // in-wave k-quad reduce (deterministic tree over kql)
#pragma unroll
    for (int mi = 0; mi < 8; ++mi)
#pragma unroll
        for (int ei = 0; ei < 8; ++ei) {
            float v = acc[mi][ei];
            v += __shfl_xor(v, 16, 64);
            v += __shfl_xor(v, 32, 64);
            acc[mi][ei] = v;
        }
    __syncthreads();

    // cross-wave reduce: sequential wave phases (deterministic order)
    for (int w = 0; w < 4; ++w) {
        if (wv == w && kql == 0) {
#pragma unroll
            for (int mi = 0; mi < 8; ++mi)
#pragma unroll
                for (int ei = 0; ei < 8; ++ei) {
                    int idx = (tg + 2 * mi) * 65 + eg + 8 * ei;
                    sc[idx] = (w == 0) ? acc[mi][ei] : sc[idx] + acc[mi][ei];
                }
        }
        __syncthreads();
    }

    if (tid < 16) {
        const float* s = &sc[tid * 65];
        float best = -1e30f, secv = -1e30f;
        int bi = 0, si = 0;
        for (int j = 0; j < NEXP; ++j) {
            float v = s[j];
            if (v > best) { secv = best; si = bi; best = v; bi = j; }
            else if (v > secv) { secv = v; si = j; }
        }
        float w0 = 1.0f / (1.0f + expf(secv - best));
        float w1 = 1.0f - w0;
        size_t t = t0 + tid;
        out[OUT_IDX_OFF + t * 2 + 0] = (float)bi;
        out[OUT_IDX_OFF + t * 2 + 1] = (float)si;
        out[OUT_W_OFF + t * 2 + 0] = w0;
        out[OUT_W_OFF + t * 2 + 1] = w1;
        wsW[t * 2 + 0] = w0;
        wsW[t * 2 + 1] = w1;
        int p0 = atomicAdd(&wsCnt[bi], 1);
        if (p0 < LCAP) wsList[bi * LCAP + p0] = (int)(t * 2 + 0);
        int p1 = atomicAdd(&wsCnt[si], 1);
        if (p1 < LCAP) wsList[si * LCAP + p1] = (int)(t * 2 + 1);
    }
}

__global__ __launch_bounds__(256, 1) void score_topk(const void* x, const void* rw,
                                                     float* out, float* wsW,
                                                     int* wsCnt, int* wsList) {
    __shared__ float xs[16 * 68];
    __shared__ float wt[64 * 68];
    __shared__ float sc[16 * 65];
    __shared__ int dc;
    int f = detect_f32((const u16*)x, &dc);
    if (f)
        score_body(LdF32{(const float*)x}, LdF32{(const float*)rw}, xs, wt, sc, out, wsW, wsCnt, wsList);
    else
        score_body(LdBF{(const u16*)x}, LdBF{(const u16*)rw}, xs, wt, sc, out, wsW, wsCnt, wsList);
}

// ---------------- Kernel B: per-expert bf16 MFMA GEMM (R11 verbatim) -------
// 1024 blocks: e = bid&63 (XCD = e%8), ti = bid>>6 (rows [16ti,16ti+16)).
// All staging loads b128; token base addresses hoisted out of k-loop.
template <class LD>
__device__ __forceinline__ void egemm_body(LD xld, LD nld,
                                           const int* wsCnt, const int* wsList,
                                           const float* wsW, float* out,
                                           u16* Ab /*16*136*/, u16* Bb /*64*136*/,
                                           int* entL /*16*/) {
    const int tid = threadIdx.x;
    const int e = blockIdx.x & 63;
    const int ti = blockIdx.x >> 6;
    const int cntE = min(wsCnt[e], LCAP);
    const int base = ti * 16;
    if (base >= cntE) return;
    const int valid = min(16, cntE - base);
    const int wv = tid >> 6;
    const int lane = tid & 63;
    const int l15 = lane & 15, quad = lane >> 4;
    const size_t nbase = (size_t)e * (DDIM * RDIM);

    if (tid < 16)
        entL[tid] = wsList[e * LCAP + base + min(tid, valid - 1)];
    __syncthreads();

    const int rowA = tid & 15;
    const int kq0 = tid >> 4;
    const size_t ttA = (size_t)(entL[rowA] >> 1) * DDIM;

    f32x4 acc = {0.f, 0.f, 0.f, 0.f};

    for (int kc = 0; kc < 8; ++kc) {
        const int k0c = kc * 128;
        if (kc > 0) __syncthreads();
#pragma unroll
        for (int h = 0; h < 4; ++h) {
            int u = tid + h * 256;
            int rq = u & 15, kp = u >> 4;
            float4 g0 = nld.ld4(nbase + (size_t)(k0c + 2 * kp) * RDIM + 4 * rq);
            float4 g1 = nld.ld4(nbase + (size_t)(k0c + 2 * kp + 1) * RDIM + 4 * rq);
            u32* bw = (u32*)Bb;
            bw[(4 * rq + 0) * 68 + kp] = pack2(g0.x, g1.x);
            bw[(4 * rq + 1) * 68 + kp] = pack2(g0.y, g1.y);
            bw[(4 * rq + 2) * 68 + kp] = pack2(g0.z, g1.z);
            bw[(4 * rq + 3) * 68 + kp] = pack2(g0.w, g1.w);
        }
        {
            float4 ga0 = xld.ld4(ttA + k0c + 4 * kq0);
            float4 ga1 = xld.ld4(ttA + k0c + 4 * (kq0 + 16));
            u32* aw = (u32*)Ab;
            aw[rowA * 68 + 2 * kq0 + 0]  = pack2(ga0.x, ga0.y);
            aw[rowA * 68 + 2 * kq0 + 1]  = pack2(ga0.z, ga0.w);
            aw[rowA * 68 + 2 * kq0 + 32] = pack2(ga1.x, ga1.y);
            aw[rowA * 68 + 2 * kq0 + 33] = pack2(ga1.z, ga1.w);
        }
        __syncthreads();

#pragma unroll
        for (int ko = 0; ko < 4; ++ko) {
            int kofs = ko * 32 + quad * 8;
            short8 bfr = *(const short8*)&Bb[(16 * wv + l15) * 136 + kofs];
            short8 af = *(const short8*)&Ab[l15 * 136 + kofs];
            acc = __builtin_amdgcn_mfma_f32_16x16x32_bf16(af, bfr, acc, 0, 0, 0);
        }
    }

    // D: row (token m) = quad*4+reg, col r = 16*wv + l15
#pragma unroll
    for (int reg = 0; reg < 4; ++reg) {
        int m = quad * 4 + reg;
        if (m < valid) {
            int t2 = entL[m];
            atomicAdd(&out[(size_t)(t2 >> 1) * RDIM + 16 * wv + l15], wsW[t2] * acc[reg]);
        }
    }
}

__global__ __launch_bounds__(256) void expert_gemm(const void* x, const void* neurons,
                                                   const int* wsCnt, const int* wsList,
                                                   const float* wsW, float* out) {
    __shared__ u16 Ab[16 * 136];
    __shared__ u16 Bb[64 * 136];
    __shared__ int entL[16];
    __shared__ int dc;
    int f = detect_f32((const u16*)x, &dc);
    if (f)
        egemm_body(LdF32{(const float*)x}, LdF32{(const float*)neurons}, wsCnt, wsList, wsW, out, Ab, Bb, entL);
    else
        egemm_body(LdBF{(const u16*)x}, LdBF{(const u16*)neurons}, wsCnt, wsList, wsW, out, Ab, Bb, entL);
}

extern "C" void kernel_launch(void* const* d_in, const int* in_sizes, int n_in,
                              void* d_out, int out_size, void* d_ws, size_t ws_size,
                              hipStream_t stream) {
    const void* x = d_in[0];
    const void* rw = d_in[1];
    const void* neurons = d_in[2];
    float* out = (float*)d_out;

    char* wsc = (char*)d_ws;
    float* wsW = (float*)wsc;                                  // 32 KB
    int* wsCnt = (int*)(wsc + 32 * 1024);                      // 256 B
    int* wsList = (int*)((char*)wsCnt + 256);                  // 256 KB

    hipMemsetAsync(wsCnt, 0, 256, stream);
    score_topk<<<256, 256, 0, stream>>>(x, rw, out, wsW, wsCnt, wsList);
    expert_gemm<<<1024, 256, 0, stream>>>(x, neurons, wsCnt, wsList, wsW, out);
}